// Round 2
// baseline (228.173 us; speedup 1.0000x reference)
//
#include <hip/hip_runtime.h>

// GradientLoss: g(x) = sqrt(gv^2 + gh^2 + eps), loss = mean(|g(in) - g(tgt)|)
// gv[h][w] = x[h+1][w] - x[h-1][w]  (zero pad)
// gh[h][w] = x[h][w+1] - x[h][w-1]  (zero pad)
// Shapes: (32, 3, 512, 512) fp32. Output: 1 fp32 scalar.

constexpr int Hh = 512;
constexpr int Ww = 512;
constexpr int PLANES = 32 * 3;          // N*C independent 2D planes
constexpr int W4 = Ww / 4;              // 128 float4 per row
constexpr int PLANE4 = Hh * W4;         // float4s per plane (65536)
constexpr int TOTAL4 = PLANES * PLANE4; // 6,291,456 (fits in int)
constexpr float EPS = 1e-6f;
constexpr float INV_N = 1.0f / ((float)PLANES * (float)Hh * (float)Ww);

__global__ __launch_bounds__(256) void grad_loss_kernel(
    const float* __restrict__ in,
    const float* __restrict__ tgt,
    float* __restrict__ out)
{
    float acc = 0.0f;
    const int stride = gridDim.x * blockDim.x;

    for (int idx = blockIdx.x * blockDim.x + threadIdx.x;
         idx < TOTAL4; idx += stride) {

        const int plane = idx >> 16;           // idx / PLANE4 (PLANE4 = 65536)
        const int rem   = idx & 65535;
        const int h     = rem >> 7;            // rem / W4  (W4 = 128)
        const int w0    = (rem & 127) << 2;    // (rem % W4) * 4
        const long base = (long)plane * (Hh * Ww) + (long)h * Ww + w0;

        const bool has_up    = (h > 0);
        const bool has_dn    = (h < Hh - 1);
        const bool has_left  = (w0 > 0);
        const bool has_right = (w0 + 4 < Ww);

        float g0[4], g1[4];

        // ---- tensor 0: input ----
        {
            const float* x = in;
            const float4 c = *reinterpret_cast<const float4*>(x + base);
            float4 up = make_float4(0.f, 0.f, 0.f, 0.f);
            float4 dn = make_float4(0.f, 0.f, 0.f, 0.f);
            if (has_up) up = *reinterpret_cast<const float4*>(x + base - Ww);
            if (has_dn) dn = *reinterpret_cast<const float4*>(x + base + Ww);
            const float left  = has_left  ? x[base - 1] : 0.f;
            const float right = has_right ? x[base + 4] : 0.f;

            const float gv0 = dn.x - up.x, gv1 = dn.y - up.y;
            const float gv2 = dn.z - up.z, gv3 = dn.w - up.w;
            const float gh0 = c.y - left,  gh1 = c.z - c.x;
            const float gh2 = c.w - c.y,   gh3 = right - c.z;

            g0[0] = sqrtf(gv0 * gv0 + gh0 * gh0 + EPS);
            g0[1] = sqrtf(gv1 * gv1 + gh1 * gh1 + EPS);
            g0[2] = sqrtf(gv2 * gv2 + gh2 * gh2 + EPS);
            g0[3] = sqrtf(gv3 * gv3 + gh3 * gh3 + EPS);
        }

        // ---- tensor 1: target ----
        {
            const float* x = tgt;
            const float4 c = *reinterpret_cast<const float4*>(x + base);
            float4 up = make_float4(0.f, 0.f, 0.f, 0.f);
            float4 dn = make_float4(0.f, 0.f, 0.f, 0.f);
            if (has_up) up = *reinterpret_cast<const float4*>(x + base - Ww);
            if (has_dn) dn = *reinterpret_cast<const float4*>(x + base + Ww);
            const float left  = has_left  ? x[base - 1] : 0.f;
            const float right = has_right ? x[base + 4] : 0.f;

            const float gv0 = dn.x - up.x, gv1 = dn.y - up.y;
            const float gv2 = dn.z - up.z, gv3 = dn.w - up.w;
            const float gh0 = c.y - left,  gh1 = c.z - c.x;
            const float gh2 = c.w - c.y,   gh3 = right - c.z;

            g1[0] = sqrtf(gv0 * gv0 + gh0 * gh0 + EPS);
            g1[1] = sqrtf(gv1 * gv1 + gh1 * gh1 + EPS);
            g1[2] = sqrtf(gv2 * gv2 + gh2 * gh2 + EPS);
            g1[3] = sqrtf(gv3 * gv3 + gh3 * gh3 + EPS);
        }

        acc += fabsf(g0[0] - g1[0]) + fabsf(g0[1] - g1[1])
             + fabsf(g0[2] - g1[2]) + fabsf(g0[3] - g1[3]);
    }

    // ---- wave reduction (64 lanes) ----
    #pragma unroll
    for (int off = 32; off > 0; off >>= 1)
        acc += __shfl_down(acc, off, 64);

    __shared__ float wsum[4];
    const int lane = threadIdx.x & 63;
    const int wid  = threadIdx.x >> 6;
    if (lane == 0) wsum[wid] = acc;
    __syncthreads();

    if (threadIdx.x == 0) {
        const float blocksum = wsum[0] + wsum[1] + wsum[2] + wsum[3];
        atomicAdd(out, blocksum * INV_N);
    }
}

extern "C" void kernel_launch(void* const* d_in, const int* in_sizes, int n_in,
                              void* d_out, int out_size, void* d_ws, size_t ws_size,
                              hipStream_t stream) {
    const float* in  = (const float*)d_in[0];
    const float* tgt = (const float*)d_in[1];
    float* out = (float*)d_out;

    // d_out is poisoned with 0xAA before every launch — zero it first.
    hipMemsetAsync(out, 0, sizeof(float), stream);

    const int block = 256;
    const int grid  = 2048;   // TOTAL4 / (2048*256) = 12 iters/thread exactly
    grad_loss_kernel<<<grid, block, 0, stream>>>(in, tgt, out);
}

// Round 3
// 213.985 us; speedup vs baseline: 1.0663x; 1.0663x over previous
//
#include <hip/hip_runtime.h>

// GradientLoss: g(x) = sqrt(gv^2 + gh^2 + eps), loss = mean(|g(in) - g(tgt)|)
// gv[h][w] = x[h+1][w] - x[h-1][w]  (zero pad), gh[h][w] = x[h][w+1] - x[h][w-1]
// Shapes: (32, 3, 512, 512) fp32 -> 96 independent 512x512 planes. Output: 1 fp32.
//
// Structure: one wave = one 8-row strip of one plane. Each lane owns 8
// consecutive columns (2x float4), so a wave covers the full 512-wide row.
// Rolling 3-row register window => every element is loaded exactly once
// (plus 2 halo rows per strip). Horizontal neighbors via __shfl, no scalar
// edge loads, no per-lane branches in the hot loop.

constexpr int H = 512, W = 512;
constexpr int PLANES = 96;            // N*C = 32*3
constexpr int R = 8;                  // rows per strip
constexpr int SPP = H / R;            // strips per plane = 64
constexpr int NSTRIPS = PLANES * SPP; // 6144 waves
constexpr int WAVES_PER_BLOCK = 4;
constexpr int NBLOCKS = NSTRIPS / WAVES_PER_BLOCK; // 1536
constexpr float EPS = 1e-6f;
constexpr float INV_N = 1.0f / ((float)PLANES * (float)H * (float)W);

__device__ __forceinline__ void load8(const float* __restrict__ p, float r[8]) {
    const float4 a = *reinterpret_cast<const float4*>(p);
    const float4 b = *reinterpret_cast<const float4*>(p + 4);
    r[0] = a.x; r[1] = a.y; r[2] = a.z; r[3] = a.w;
    r[4] = b.x; r[5] = b.y; r[6] = b.z; r[7] = b.w;
}

__device__ __forceinline__ void zero8(float r[8]) {
    #pragma unroll
    for (int i = 0; i < 8; ++i) r[i] = 0.f;
}

// gradient magnitude for this lane's 8 pixels of row h, given rows h-1,h,h+1
__device__ __forceinline__ void grad8(const float up[8], const float cu[8],
                                      const float dn[8], bool lane0, bool lane63,
                                      float g[8]) {
    float lw = __shfl_up(cu[7], 1, 64);    // lane-1's col 7  (w-1 for col 0)
    float rw = __shfl_down(cu[0], 1, 64);  // lane+1's col 0  (w+1 for col 7)
    if (lane0)  lw = 0.f;                  // w == 0   -> zero pad
    if (lane63) rw = 0.f;                  // w == 511 -> zero pad

    float gh[8];
    gh[0] = cu[1] - lw;
    #pragma unroll
    for (int i = 1; i < 7; ++i) gh[i] = cu[i + 1] - cu[i - 1];
    gh[7] = rw - cu[6];

    #pragma unroll
    for (int i = 0; i < 8; ++i) {
        const float gv = dn[i] - up[i];
        g[i] = __builtin_amdgcn_sqrtf(fmaf(gv, gv, fmaf(gh[i], gh[i], EPS)));
    }
}

__global__ __launch_bounds__(256) void grad_loss_kernel(
    const float* __restrict__ in,
    const float* __restrict__ tgt,
    float* __restrict__ out)
{
    const int wid   = blockIdx.x * WAVES_PER_BLOCK + (threadIdx.x >> 6);
    const int lane  = threadIdx.x & 63;
    const int plane = wid / SPP;
    const int strip = wid - plane * SPP;
    const int h0    = strip * R;

    const int base = plane * (H * W) + h0 * W + lane * 8;
    const float* __restrict__ pi = in  + base;
    const float* __restrict__ pt = tgt + base;

    const bool lane0  = (lane == 0);
    const bool lane63 = (lane == 63);
    const bool lastStrip = (h0 + R == H);   // wave-uniform

    // rolling window: [k%3]=row h-1, [(k+1)%3]=row h, [(k+2)%3]=row h+1
    float ib[3][8], tb[3][8];
    if (h0 == 0) { zero8(ib[0]); zero8(tb[0]); }                 // wave-uniform
    else         { load8(pi - W, ib[0]); load8(pt - W, tb[0]); }
    load8(pi, ib[1]); load8(pt, tb[1]);

    float acc = 0.f;

    #pragma unroll
    for (int k = 0; k < R; ++k) {
        const int iprev = k % 3, icur = (k + 1) % 3, inxt = (k + 2) % 3;

        if (k == R - 1 && lastStrip) {       // compile-time false for k<R-1
            zero8(ib[inxt]); zero8(tb[inxt]);
        } else {
            load8(pi + (k + 1) * W, ib[inxt]);
            load8(pt + (k + 1) * W, tb[inxt]);
        }

        float gi[8], gt[8];
        grad8(ib[iprev], ib[icur], ib[inxt], lane0, lane63, gi);
        grad8(tb[iprev], tb[icur], tb[inxt], lane0, lane63, gt);

        #pragma unroll
        for (int i = 0; i < 8; ++i) acc += fabsf(gi[i] - gt[i]);
    }

    // ---- wave reduction (64 lanes) ----
    #pragma unroll
    for (int off = 32; off > 0; off >>= 1)
        acc += __shfl_down(acc, off, 64);

    __shared__ float wsum[WAVES_PER_BLOCK];
    const int w = threadIdx.x >> 6;
    if (lane == 0) wsum[w] = acc;
    __syncthreads();

    if (threadIdx.x == 0) {
        const float s = wsum[0] + wsum[1] + wsum[2] + wsum[3];
        atomicAdd(out, s * INV_N);
    }
}

extern "C" void kernel_launch(void* const* d_in, const int* in_sizes, int n_in,
                              void* d_out, int out_size, void* d_ws, size_t ws_size,
                              hipStream_t stream) {
    const float* in  = (const float*)d_in[0];
    const float* tgt = (const float*)d_in[1];
    float* out = (float*)d_out;

    // d_out is poisoned with 0xAA before every launch — zero it first.
    hipMemsetAsync(out, 0, sizeof(float), stream);

    grad_loss_kernel<<<NBLOCKS, 64 * WAVES_PER_BLOCK, 0, stream>>>(in, tgt, out);
}

// Round 4
// 213.956 us; speedup vs baseline: 1.0664x; 1.0001x over previous
//
#include <hip/hip_runtime.h>

// GradientLoss: g(x) = sqrt(gv^2 + gh^2 + eps), loss = mean(|g(in) - g(tgt)|)
// gv[h][w] = x[h+1][w] - x[h-1][w]  (zero pad), gh[h][w] = x[h][w+1] - x[h][w-1]
// Shapes: (32, 3, 512, 512) fp32 -> 96 independent 512x512 planes. Output: 1 fp32.
//
// R4: wave = 4-row strip of one plane, covering the FULL 512-wide row per
// iteration: lane i owns cols [4i..4i+3] (part A) and [256+4i..256+4i+3]
// (part B) — two dense float4 loads (16B/lane stride, perfectly coalesced).
// Rolling 3-row register window; horizontal neighbors via shfl (incl. 2
// broadcasts for the col-255/256 seam). 12288 waves for latency hiding.

constexpr int H = 512, W = 512;
constexpr int PLANES = 96;             // N*C = 32*3
constexpr int R = 4;                   // rows per strip
constexpr int SPP = H / R;             // 128 strips per plane
constexpr int NSTRIPS = PLANES * SPP;  // 12288 waves
constexpr int WPB = 4;                 // waves per block
constexpr int NBLOCKS = NSTRIPS / WPB; // 3072 blocks
constexpr float EPS = 1e-6f;
constexpr float INV_N = 1.0f / ((float)PLANES * (float)H * (float)W);

struct Row { float4 a, b; };           // cols [4i..4i+3], [256+4i..256+4i+3]

__device__ __forceinline__ Row loadRow(const float* __restrict__ p) {
    Row r;
    r.a = *reinterpret_cast<const float4*>(p);
    r.b = *reinterpret_cast<const float4*>(p + 256);
    return r;
}

__device__ __forceinline__ Row zeroRow() {
    Row r;
    r.a = make_float4(0.f, 0.f, 0.f, 0.f);
    r.b = make_float4(0.f, 0.f, 0.f, 0.f);
    return r;
}

// gradient magnitude for this lane's 8 pixels of the current row
__device__ __forceinline__ void gradRow(const Row& up, const Row& cu, const Row& dn,
                                        bool lane0, bool lane63, float g[8]) {
    float lwA = __shfl_up(cu.a.w, 1, 64);      // col 4i-1
    float rwA = __shfl_down(cu.a.x, 1, 64);    // col 4i+4
    float lwB = __shfl_up(cu.b.w, 1, 64);      // col 256+4i-1
    float rwB = __shfl_down(cu.b.x, 1, 64);    // col 256+4i+4
    const float c256 = __shfl(cu.b.x, 0, 64);  // col 256 (seam)
    const float c255 = __shfl(cu.a.w, 63, 64); // col 255 (seam)
    if (lane0)  { lwA = 0.f;  lwB = c255; }    // w=0 zero pad / seam
    if (lane63) { rwA = c256; rwB = 0.f;  }    // seam / w=511 zero pad

    const float ghA0 = cu.a.y - lwA;
    const float ghA1 = cu.a.z - cu.a.x;
    const float ghA2 = cu.a.w - cu.a.y;
    const float ghA3 = rwA    - cu.a.z;
    const float ghB0 = cu.b.y - lwB;
    const float ghB1 = cu.b.z - cu.b.x;
    const float ghB2 = cu.b.w - cu.b.y;
    const float ghB3 = rwB    - cu.b.z;

    const float gvA0 = dn.a.x - up.a.x, gvA1 = dn.a.y - up.a.y;
    const float gvA2 = dn.a.z - up.a.z, gvA3 = dn.a.w - up.a.w;
    const float gvB0 = dn.b.x - up.b.x, gvB1 = dn.b.y - up.b.y;
    const float gvB2 = dn.b.z - up.b.z, gvB3 = dn.b.w - up.b.w;

    g[0] = __builtin_amdgcn_sqrtf(fmaf(gvA0, gvA0, fmaf(ghA0, ghA0, EPS)));
    g[1] = __builtin_amdgcn_sqrtf(fmaf(gvA1, gvA1, fmaf(ghA1, ghA1, EPS)));
    g[2] = __builtin_amdgcn_sqrtf(fmaf(gvA2, gvA2, fmaf(ghA2, ghA2, EPS)));
    g[3] = __builtin_amdgcn_sqrtf(fmaf(gvA3, gvA3, fmaf(ghA3, ghA3, EPS)));
    g[4] = __builtin_amdgcn_sqrtf(fmaf(gvB0, gvB0, fmaf(ghB0, ghB0, EPS)));
    g[5] = __builtin_amdgcn_sqrtf(fmaf(gvB1, gvB1, fmaf(ghB1, ghB1, EPS)));
    g[6] = __builtin_amdgcn_sqrtf(fmaf(gvB2, gvB2, fmaf(ghB2, ghB2, EPS)));
    g[7] = __builtin_amdgcn_sqrtf(fmaf(gvB3, gvB3, fmaf(ghB3, ghB3, EPS)));
}

__global__ __launch_bounds__(256) void grad_loss_kernel(
    const float* __restrict__ src0,
    const float* __restrict__ src1,
    float* __restrict__ out)
{
    const int wid   = blockIdx.x * WPB + (threadIdx.x >> 6);
    const int lane  = threadIdx.x & 63;
    const int plane = wid >> 7;            // / SPP (SPP = 128)
    const int strip = wid & 127;
    const int h0    = strip * R;

    const int base = plane * (H * W) + h0 * W + lane * 4;
    const float* __restrict__ pi = src0 + base;
    const float* __restrict__ pt = src1 + base;

    const bool lane0  = (lane == 0);
    const bool lane63 = (lane == 63);
    const bool lastStrip = (h0 + R == H);  // wave-uniform

    Row wi[3], wt[3];
    if (h0 == 0) { wi[0] = zeroRow(); wt[0] = zeroRow(); }       // wave-uniform
    else         { wi[0] = loadRow(pi - W); wt[0] = loadRow(pt - W); }
    wi[1] = loadRow(pi); wt[1] = loadRow(pt);

    float acc = 0.f;

    #pragma unroll
    for (int k = 0; k < R; ++k) {
        const int ip = k % 3, ic = (k + 1) % 3, nx = (k + 2) % 3;

        if (k == R - 1 && lastStrip) {     // compile-time false for k < R-1
            wi[nx] = zeroRow(); wt[nx] = zeroRow();
        } else {
            wi[nx] = loadRow(pi + (k + 1) * W);
            wt[nx] = loadRow(pt + (k + 1) * W);
        }

        float gi[8], gt[8];
        gradRow(wi[ip], wi[ic], wi[nx], lane0, lane63, gi);
        gradRow(wt[ip], wt[ic], wt[nx], lane0, lane63, gt);

        #pragma unroll
        for (int i = 0; i < 8; ++i) acc += fabsf(gi[i] - gt[i]);
    }

    // ---- wave reduction (64 lanes) ----
    #pragma unroll
    for (int off = 32; off > 0; off >>= 1)
        acc += __shfl_down(acc, off, 64);

    __shared__ float wsum[WPB];
    const int w = threadIdx.x >> 6;
    if (lane == 0) wsum[w] = acc;
    __syncthreads();

    if (threadIdx.x == 0) {
        const float s = wsum[0] + wsum[1] + wsum[2] + wsum[3];
        atomicAdd(out, s * INV_N);
    }
}

extern "C" void kernel_launch(void* const* d_in, const int* in_sizes, int n_in,
                              void* d_out, int out_size, void* d_ws, size_t ws_size,
                              hipStream_t stream) {
    const float* in  = (const float*)d_in[0];
    const float* tgt = (const float*)d_in[1];
    float* out = (float*)d_out;

    // d_out is poisoned with 0xAA before every launch — zero it first.
    hipMemsetAsync(out, 0, sizeof(float), stream);

    grad_loss_kernel<<<NBLOCKS, 64 * WPB, 0, stream>>>(in, tgt, out);
}